// Round 3
// baseline (6600.077 us; speedup 1.0000x reference)
//
#include <hip/hip_runtime.h>
#include <stdint.h>

// Problem constants (B=256, D=1024, T=128)
#define B_ROWS 256
#define DDIM   1024
#define TSTEPS 128
#define THREE_D 3072
#define OSTRIDE (TSTEPS * DDIM)   // out row stride (per batch row)

typedef short bf16x8 __attribute__((ext_vector_type(8)));
typedef float f32x4  __attribute__((ext_vector_type(4)));
typedef unsigned short u16x8 __attribute__((ext_vector_type(8)));

static __device__ __forceinline__ unsigned short f2bf(float f) {
    union { float f; uint32_t u; } v; v.f = f;
    uint32_t u = v.u;
    uint32_t r = u + 0x7FFFu + ((u >> 16) & 1u);   // round-to-nearest-even
    return (unsigned short)(r >> 16);
}
static __device__ __forceinline__ float bf2f(unsigned short h) {
    union { uint32_t u; float f; } v; v.u = ((uint32_t)h) << 16; return v.f;
}

// ---------------------------------------------------------------------------
// Pack folded weights (steps>=1) into hi+lo bf16 pairs in MFMA B-fragment
// order. M = [Wz+Uz | Wr+Ur | Wh | Uh]  (f32 fold, then split).
// Layout: pack[ntile(0..255)][ktile(0..31)][lane(0..63)][j(0..7)]
//   col = ntile*16 + (lane&15),  k = ktile*32 + (lane>>4)*8 + j
// ---------------------------------------------------------------------------
__global__ __launch_bounds__(256) void pack_kernel(
    const float* __restrict__ W, const float* __restrict__ U,
    unsigned short* __restrict__ phi, unsigned short* __restrict__ plo)
{
    int t = blockIdx.x * 256 + threadIdx.x;   // 524288 threads
    int lane  = t & 63;
    int ktile = (t >> 6) & 31;
    int ntile = t >> 11;                       // 0..255
    int col = ntile * 16 + (lane & 15);
    int q = col >> 10;                         // wave-uniform
    int d = col & 1023;
    int k8 = ktile * 32 + ((lane >> 4) << 3);

    u16x8 ohi, olo;
    #pragma unroll
    for (int j = 0; j < 8; ++j) {
        int k = k8 + j;
        const float* wr = W + (size_t)k * THREE_D;
        const float* ur = U + (size_t)k * THREE_D;
        float v;
        if (q == 0)      v = wr[d] + ur[d];
        else if (q == 1) v = wr[1024 + d] + ur[1024 + d];
        else if (q == 2) v = wr[2048 + d];
        else             v = ur[2048 + d];
        unsigned short hi = f2bf(v);
        ohi[j] = hi;
        olo[j] = f2bf(v - bf2f(hi));
    }
    size_t base = ((size_t)(ntile * 32 + ktile) * 64 + lane) * 8;
    *(u16x8*)(phi + base) = ohi;
    *(u16x8*)(plo + base) = olo;
}

// Step-0 packed matrix: [Uz | Ur | 0 | Uh]  (hi+lo). Same layout.
__global__ __launch_bounds__(256) void pack0_kernel(
    const float* __restrict__ U,
    unsigned short* __restrict__ phi, unsigned short* __restrict__ plo)
{
    int t = blockIdx.x * 256 + threadIdx.x;
    int lane  = t & 63;
    int ktile = (t >> 6) & 31;
    int ntile = t >> 11;
    int col = ntile * 16 + (lane & 15);
    int q = col >> 10;
    int d = col & 1023;
    int k8 = ktile * 32 + ((lane >> 4) << 3);

    u16x8 ohi, olo;
    #pragma unroll
    for (int j = 0; j < 8; ++j) {
        int k = k8 + j;
        const float* ur = U + (size_t)k * THREE_D;
        float v;
        if (q == 0)      v = ur[d];
        else if (q == 1) v = ur[1024 + d];
        else if (q == 2) v = 0.0f;
        else             v = ur[2048 + d];
        unsigned short hi = f2bf(v);
        ohi[j] = hi;
        olo[j] = f2bf(v - bf2f(hi));
    }
    size_t base = ((size_t)(ntile * 32 + ktile) * 64 + lane) * 8;
    *(u16x8*)(phi + base) = ohi;
    *(u16x8*)(plo + base) = olo;
}

// Quantize x (f32 initial state) into hi+lo bf16 state buffers.
__global__ __launch_bounds__(256) void init_x(
    const float* __restrict__ x,
    unsigned short* __restrict__ xh, unsigned short* __restrict__ xl)
{
    int i = blockIdx.x * 256 + threadIdx.x;
    if (i < B_ROWS * DDIM) {
        float v = x[i];
        unsigned short h = f2bf(v);
        xh[i] = h;
        xl[i] = f2bf(v - bf2f(h));
    }
}

// ---------------------------------------------------------------------------
// One GRU step, fused GEMM (split-bf16, 3 cross terms) + gates.
// Grid 256 blocks (1/CU): dt = blk&63 (16 dims), rt = blk>>6 (64 rows).
// Block = 1024 threads = 16 waves = (q in 0..3) x (kq in 0..3, K-quarter).
//   -> 4 waves/SIMD for latency hiding (round-2 had 1/SIMD: 34 us/step).
// Per wave: 8 ktiles x 4 m-tiles x 3 MFMA = 96 MFMA into f32 acc; kq-partials
// combined via LDS f32 atomics (17-padded rows, conflict-free).
// f32 prev state read from hprev (x for t=0, out[t-1] otherwise).
// ---------------------------------------------------------------------------
__global__ __launch_bounds__(1024) void gru_step(
    const unsigned short* __restrict__ phi,
    const unsigned short* __restrict__ plo,
    const unsigned short* __restrict__ hbh_in,
    const unsigned short* __restrict__ hbl_in,
    const float* __restrict__ bias,
    const float* __restrict__ hprev, int hstride,
    float* __restrict__ out_t,
    unsigned short* __restrict__ hbh_out,
    unsigned short* __restrict__ hbl_out)
{
    __shared__ float pbuf[4][64][17];   // [q][row][col], +1 pad -> 17.4 KB
    const int tid  = threadIdx.x;
    const int w    = tid >> 6;
    const int lane = tid & 63;
    const int q    = w & 3;             // gate quarter
    const int kq   = w >> 2;            // K quarter (256 k each)
    const int dt   = blockIdx.x & 63;   // dim tile (16 dims)
    const int rt   = blockIdx.x >> 6;   // row tile (64 rows)
    const int llow = lane & 15;
    const int lhi  = lane >> 4;

    // zero the partial buffer
    float* pf = &pbuf[0][0][0];
    for (int i = tid; i < 4 * 64 * 17; i += 1024) pf[i] = 0.0f;
    __syncthreads();

    f32x4 acc[4] = {f32x4{0,0,0,0}, f32x4{0,0,0,0}, f32x4{0,0,0,0}, f32x4{0,0,0,0}};

    const int ntile = q * 64 + dt;
    const unsigned short* bhp = phi + (size_t)ntile * 16384 + (size_t)kq * 4096 + (size_t)lane * 8;
    const unsigned short* blp = plo + (size_t)ntile * 16384 + (size_t)kq * 4096 + (size_t)lane * 8;
    const size_t arow = (size_t)(rt * 64 + llow) * DDIM + kq * 256 + lhi * 8;
    const unsigned short* ahp = hbh_in + arow;
    const unsigned short* alp = hbl_in + arow;

    #pragma unroll 2
    for (int kt = 0; kt < 8; ++kt) {
        bf16x8 bh = *(const bf16x8*)(bhp + kt * 512);
        bf16x8 bl = *(const bf16x8*)(blp + kt * 512);
        const int koff = kt * 32;
        #pragma unroll
        for (int m = 0; m < 4; ++m) {
            bf16x8 ah = *(const bf16x8*)(ahp + m * 16 * DDIM + koff);
            bf16x8 al = *(const bf16x8*)(alp + m * 16 * DDIM + koff);
            acc[m] = __builtin_amdgcn_mfma_f32_16x16x32_bf16(ah, bh, acc[m], 0, 0, 0);
            acc[m] = __builtin_amdgcn_mfma_f32_16x16x32_bf16(al, bh, acc[m], 0, 0, 0);
            acc[m] = __builtin_amdgcn_mfma_f32_16x16x32_bf16(ah, bl, acc[m], 0, 0, 0);
        }
    }

    // C/D layout: col = lane&15, row = (lane>>4)*4 + reg  [measured m89]
    #pragma unroll
    for (int m = 0; m < 4; ++m) {
        #pragma unroll
        for (int r = 0; r < 4; ++r) {
            atomicAdd(&pbuf[q][m * 16 + lhi * 4 + r][llow], acc[m][r]);  // ds_add_f32
        }
    }
    __syncthreads();

    // Gate epilogue: 64x16 = 1024 elements, one per thread
    {
        int row = tid >> 4, col = tid & 15;
        int d = dt * 16 + col;
        int grow = rt * 64 + row;
        float gz = pbuf[0][row][col] + bias[d];
        float gr = pbuf[1][row][col] + bias[1024 + d];
        float gx = pbuf[2][row][col] + bias[2048 + d];
        float gu = pbuf[3][row][col];
        float z  = 1.0f / (1.0f + __expf(-gz));
        float r  = 1.0f / (1.0f + __expf(-gr));
        float hh = tanhf(gx + r * gu);
        float hp = hprev[(size_t)grow * hstride + d];   // exact f32 prev state
        float hn = z * hp + (1.0f - z) * hh;
        out_t[(size_t)grow * OSTRIDE + d] = hn;
        unsigned short hi = f2bf(hn);
        size_t hoff = (size_t)grow * DDIM + d;
        hbh_out[hoff] = hi;
        hbl_out[hoff] = f2bf(hn - bf2f(hi));
    }
}

// ---------------------------------------------------------------------------
// Fallback step 0 in exact f32 (used only if workspace < 34 MB).
// ---------------------------------------------------------------------------
__global__ __launch_bounds__(256) void gru_step0(
    const float* __restrict__ x, const float* __restrict__ U,
    const float* __restrict__ bias,
    float* __restrict__ out,
    unsigned short* __restrict__ hbh, unsigned short* __restrict__ hbl)
{
    __shared__ float xt[16][64];
    const int tid = threadIdx.x;
    const int c   = tid & 63;
    const int rg  = tid >> 6;
    const int dt  = blockIdx.x & 15;
    const int rt  = blockIdx.x >> 4;

    float acc[4][3];
    #pragma unroll
    for (int rr = 0; rr < 4; ++rr) { acc[rr][0] = 0.f; acc[rr][1] = 0.f; acc[rr][2] = 0.f; }

    for (int kc = 0; kc < 16; ++kc) {
        #pragma unroll
        for (int i = 0; i < 4; ++i) {
            int e = i * 256 + tid;
            int row = e >> 6, kk = e & 63;
            xt[row][kk] = x[(size_t)(rt * 16 + row) * DDIM + kc * 64 + kk];
        }
        __syncthreads();
        #pragma unroll 4
        for (int kk = 0; kk < 64; ++kk) {
            int k = kc * 64 + kk;
            const float* up = U + (size_t)k * THREE_D + dt * 64 + c;
            float uz = up[0], ur = up[1024], uh = up[2048];
            #pragma unroll
            for (int rr = 0; rr < 4; ++rr) {
                float xv = xt[rg * 4 + rr][kk];
                acc[rr][0] += xv * uz;
                acc[rr][1] += xv * ur;
                acc[rr][2] += xv * uh;
            }
        }
        __syncthreads();
    }

    int d = dt * 64 + c;
    #pragma unroll
    for (int rr = 0; rr < 4; ++rr) {
        int row = rt * 16 + rg * 4 + rr;
        float z  = 1.0f / (1.0f + __expf(-(acc[rr][0] + bias[d])));
        float r  = 1.0f / (1.0f + __expf(-(acc[rr][1] + bias[1024 + d])));
        float hh = tanhf(bias[2048 + d] + r * acc[rr][2]);
        float hp = x[(size_t)row * DDIM + d];
        float hn = z * hp + (1.0f - z) * hh;
        out[(size_t)row * OSTRIDE + d] = hn;
        unsigned short hi = f2bf(hn);
        size_t off = (size_t)row * DDIM + d;
        hbh[off] = hi;
        hbl[off] = f2bf(hn - bf2f(hi));
    }
}

extern "C" void kernel_launch(void* const* d_in, const int* in_sizes, int n_in,
                              void* d_out, int out_size, void* d_ws, size_t ws_size,
                              hipStream_t stream) {
    const float* x = (const float*)d_in[0];
    const float* W = (const float*)d_in[1];
    const float* U = (const float*)d_in[2];
    const float* b = (const float*)d_in[3];
    float* out = (float*)d_out;

    char* ws = (char*)d_ws;
    // ws layout: p1 (16 MB) + h buffers (2 MB) [+ p0 (16 MB) if room -> 34 MB]
    unsigned short* p1h = (unsigned short*)ws;                      // 8 MB
    unsigned short* p1l = (unsigned short*)(ws + (8u << 20));       // 8 MB
    char* hbase = ws + (16u << 20);
    unsigned short* hbh[2] = { (unsigned short*)hbase,
                               (unsigned short*)(hbase + (512u << 10)) };
    unsigned short* hbl[2] = { (unsigned short*)(hbase + (1024u << 10)),
                               (unsigned short*)(hbase + (1536u << 10)) };
    unsigned short* p0h = (unsigned short*)(ws + (18u << 20));      // 8 MB (optional)
    unsigned short* p0l = (unsigned short*)(ws + (26u << 20));      // 8 MB (optional)
    const bool mfma_step0 = (ws_size >= (34ull << 20));             // ws_size is constant per harness

    hipLaunchKernelGGL(pack_kernel, dim3(2048), dim3(256), 0, stream, W, U, p1h, p1l);

    if (mfma_step0) {
        hipLaunchKernelGGL(pack0_kernel, dim3(2048), dim3(256), 0, stream, U, p0h, p0l);
        // stage quantized x in the [1] buffers (step 0 writes [0], step 1 reads [0] -> no clash)
        hipLaunchKernelGGL(init_x, dim3(1024), dim3(256), 0, stream, x, hbh[1], hbl[1]);
        hipLaunchKernelGGL(gru_step, dim3(256), dim3(1024), 0, stream,
                           p0h, p0l, hbh[1], hbl[1], b,
                           x, DDIM,                 // prev f32 state = x
                           out,                     // t = 0 slice
                           hbh[0], hbl[0]);
    } else {
        hipLaunchKernelGGL(gru_step0, dim3(256), dim3(256), 0, stream, x, U, b,
                           out, hbh[0], hbl[0]);
    }

    for (int t = 1; t < TSTEPS; ++t) {
        int src = (t - 1) & 1;
        int dst = t & 1;
        hipLaunchKernelGGL(gru_step, dim3(256), dim3(1024), 0, stream,
                           p1h, p1l, hbh[src], hbl[src], b,
                           out + (size_t)(t - 1) * DDIM, OSTRIDE,
                           out + (size_t)t * DDIM,
                           hbh[dst], hbl[dst]);
    }
}